// Round 3
// baseline (374.581 us; speedup 1.0000x reference)
//
#include <hip/hip_runtime.h>
#include <cstdint>
#include <cstddef>

#define B_   2
#define S_   21760
#define M_   (B_ * S_)     // 43520
#define D_   256
#define DFF_ 1024
#define EPS_ 1e-5f

typedef __attribute__((ext_vector_type(8))) short short8;
typedef __attribute__((ext_vector_type(4))) float f32x4;

__device__ __forceinline__ ushort f2bf(float f) {
    uint x = __float_as_uint(f);
    return (ushort)((x + 0x7fffu + ((x >> 16) & 1u)) >> 16);
}
__device__ __forceinline__ float bf2f(ushort u) {
    return __uint_as_float(((uint)u) << 16);
}

__device__ __constant__ int c_lH[4] = {128, 64, 32, 16};
__device__ __constant__ int c_lW[4] = {128, 64, 32, 16};
__device__ __constant__ int c_lS[4] = {0, 16384, 20480, 21504};

// ---------------------------------------------------------------------------
// One-shot weight transpose+convert for ALL weights + off/attn bias concat.
// WT layout (ushort offsets): val@0, offattn@65536 (384xK rows: 0-255=W_off,
// 256-383=W_attn), out@163840, ff1@229376, ff2@491520. Total 753664 elems.
// Tail 384 threads build bias_oa = [b_off | b_attn].
// ---------------------------------------------------------------------------
__global__ __launch_bounds__(256) void wconv_all(
    const float* __restrict__ Wval, const float* __restrict__ Woff,
    const float* __restrict__ Wattn, const float* __restrict__ Wout,
    const float* __restrict__ Wff1, const float* __restrict__ Wff2,
    const float* __restrict__ boff, const float* __restrict__ battn,
    ushort* __restrict__ WT, float* __restrict__ bias_oa)
{
    const int i = blockIdx.x * 256 + threadIdx.x;
    if (i < 65536) {                       // W_val [256][256] -> [n][k]
        const int n = i >> 8, k = i & 255;
        WT[i] = f2bf(Wval[(size_t)k * 256 + n]);
    } else if (i < 163840) {               // off+attn fused [384][256]
        const int j = i - 65536;
        const int n = j >> 8, k = j & 255;
        WT[i] = (n < 256) ? f2bf(Woff[(size_t)k * 256 + n])
                          : f2bf(Wattn[(size_t)k * 128 + (n - 256)]);
    } else if (i < 229376) {               // W_out [256][256]
        const int j = i - 163840;
        const int n = j >> 8, k = j & 255;
        WT[i] = f2bf(Wout[(size_t)k * 256 + n]);
    } else if (i < 491520) {               // W_ff1 [1024 n][256 k]
        const int j = i - 229376;
        const int n = j >> 8, k = j & 255;
        WT[i] = f2bf(Wff1[(size_t)k * 1024 + n]);
    } else if (i < 753664) {               // W_ff2 [256 n][1024 k]
        const int j = i - 491520;
        const int n = j >> 10, k = j & 1023;
        WT[i] = f2bf(Wff2[(size_t)k * 256 + n]);
    } else if (i < 753664 + 384) {
        const int j = i - 753664;
        bias_oa[j] = (j < 256) ? boff[j] : battn[j - 256];
    }
}

// ---------------------------------------------------------------------------
// src_bf = bf16(src); q_bf = bf16(src + pos)
// ---------------------------------------------------------------------------
__global__ __launch_bounds__(256) void cvt_pair(
    const float* __restrict__ src, const float* __restrict__ pos,
    ushort* __restrict__ sb, ushort* __restrict__ qb)
{
    const size_t i = ((size_t)blockIdx.x * 256 + threadIdx.x) * 4;
    if (i >= (size_t)M_ * 256) return;
    const float4 s = *(const float4*)(src + i);
    const float4 p = *(const float4*)(pos + i);
    ushort4 so, qo;
    so.x = f2bf(s.x); so.y = f2bf(s.y); so.z = f2bf(s.z); so.w = f2bf(s.w);
    qo.x = f2bf(s.x + p.x); qo.y = f2bf(s.y + p.y);
    qo.z = f2bf(s.z + p.z); qo.w = f2bf(s.w + p.w);
    *(ushort4*)(sb + i) = so;
    *(ushort4*)(qb + i) = qo;
}

// ---------------------------------------------------------------------------
// bf16 MFMA GEMM: 128x128 tile, BK=32, 4 waves, 4x4 16x16x32 fragments.
// mode 0: C row-major [M][N] bf16.
// mode 1: C head-major value layout [b][h][loc][32] (for sampling locality).
// ---------------------------------------------------------------------------
__global__ __launch_bounds__(256) void mgemm(
    const ushort* __restrict__ A, const ushort* __restrict__ WT,
    const float* __restrict__ bias, ushort* __restrict__ C,
    int M, int N, int K, int relu, int mode)
{
    __shared__ __align__(16) ushort Als[128 * 32];
    __shared__ __align__(16) ushort Bls[128 * 32];

    const int tid = threadIdx.x;
    const int wv = tid >> 6, ln = tid & 63;
    const int m0 = blockIdx.y << 7, n0 = blockIdx.x << 7;
    const int wm = wv >> 1, wn = wv & 1;

    const int lrow = ln >> 2, lcol = (ln & 3) * 8;

    f32x4 acc[4][4];
    const f32x4 zz = {0.f, 0.f, 0.f, 0.f};
    #pragma unroll
    for (int i = 0; i < 4; i++)
        #pragma unroll
        for (int j = 0; j < 4; j++) acc[i][j] = zz;

    for (int k0 = 0; k0 < K; k0 += 32) {
        __syncthreads();
        #pragma unroll
        for (int r = 0; r < 2; ++r) {
            const int c = r * 4 + wv;
            const ushort* ga = A + (size_t)(m0 + c * 16 + lrow) * K + k0 + lcol;
            __builtin_amdgcn_global_load_lds(
                (const __attribute__((address_space(1))) uint*)ga,
                (__attribute__((address_space(3))) uint*)(Als + c * 512), 16, 0, 0);
            const ushort* gb = WT + (size_t)(n0 + c * 16 + lrow) * K + k0 + lcol;
            __builtin_amdgcn_global_load_lds(
                (const __attribute__((address_space(1))) uint*)gb,
                (__attribute__((address_space(3))) uint*)(Bls + c * 512), 16, 0, 0);
        }
        __syncthreads();

        const int fr = ln & 15, kb = (ln >> 4) * 8;
        short8 af[4], bfr[4];
        #pragma unroll
        for (int i = 0; i < 4; i++)
            af[i] = *(const short8*)&Als[(wm * 64 + i * 16 + fr) * 32 + kb];
        #pragma unroll
        for (int j = 0; j < 4; j++)
            bfr[j] = *(const short8*)&Bls[(wn * 64 + j * 16 + fr) * 32 + kb];
        #pragma unroll
        for (int i = 0; i < 4; i++)
            #pragma unroll
            for (int j = 0; j < 4; j++)
                acc[i][j] = __builtin_amdgcn_mfma_f32_16x16x32_bf16(
                    af[i], bfr[j], acc[i][j], 0, 0, 0);
    }

    const int fr = ln & 15, rq = (ln >> 4) * 4;
    #pragma unroll
    for (int j = 0; j < 4; j++) {
        const int col = n0 + wn * 64 + j * 16 + fr;
        const float bv = bias[col];
        #pragma unroll
        for (int i = 0; i < 4; i++) {
            #pragma unroll
            for (int r = 0; r < 4; r++) {
                const int row = m0 + wm * 64 + i * 16 + rq + r;
                float v = acc[i][j][r] + bv;
                if (relu) v = fmaxf(v, 0.f);
                if (mode == 0) {
                    C[(size_t)row * N + col] = f2bf(v);
                } else {
                    const int b = (row >= S_) ? 1 : 0;
                    const int loc = row - b * S_;
                    const int h = col >> 5, ch = col & 31;
                    C[((size_t)(b * 8 + h) * S_ + loc) * 32 + ch] = f2bf(v);
                }
            }
        }
    }
}

// ---------------------------------------------------------------------------
// Deformable sampling with head-major value + inline softmax.
// Block = 8 queries x (8 heads x 4 chan-grps); thread owns 8 channels.
// offaw[q][384]: cols 0..255 = offsets (h*32 + s*2 + {x,y}); 256..383 = raw
// attention logits (h*16 + s), softmaxed here in registers.
// ---------------------------------------------------------------------------
__global__ __launch_bounds__(256) void sample3(
    const ushort* __restrict__ value, const ushort* __restrict__ offaw,
    const float* __restrict__ refp, ushort* __restrict__ samp)
{
    const int t = threadIdx.x;
    const int q = blockIdx.x * 8 + (t >> 5);
    const int w = t & 31;
    const int h = w >> 2, cg = w & 3;
    const int b = q / S_;

    const float* rp = refp + (size_t)q * 8;
    const ushort* ofq = offaw + (size_t)q * 384 + h * 32;
    const ushort* awq = offaw + (size_t)q * 384 + 256 + h * 16;
    const ushort* vb = value + (size_t)(b * 8 + h) * S_ * 32 + cg * 8;

    // inline softmax over the 16 logits of this (q,h)
    float pw[16];
    float mx = -1e30f;
    #pragma unroll
    for (int s = 0; s < 16; s++) { pw[s] = bf2f(awq[s]); mx = fmaxf(mx, pw[s]); }
    float sum = 0.f;
    #pragma unroll
    for (int s = 0; s < 16; s++) { pw[s] = __expf(pw[s] - mx); sum += pw[s]; }
    const float inv = 1.f / sum;

    float acc[8] = {0.f, 0.f, 0.f, 0.f, 0.f, 0.f, 0.f, 0.f};

    #pragma unroll
    for (int l = 0; l < 4; l++) {
        const int Wl = c_lW[l], Hl = c_lH[l], st = c_lS[l];
        const float fW = (float)Wl, fH = (float)Hl;
        const float rx = rp[l * 2], ry = rp[l * 2 + 1];
        #pragma unroll
        for (int p = 0; p < 4; p++) {
            const int s = l * 4 + p;
            const float a = pw[s] * inv;
            const float x = (rx + bf2f(ofq[s * 2]) / fW) * fW - 0.5f;
            const float y = (ry + bf2f(ofq[s * 2 + 1]) / fH) * fH - 0.5f;
            const float fx0 = floorf(x), fy0 = floorf(y);
            const float dx = x - fx0, dy = y - fy0;
            const int x0 = (int)fx0, y0 = (int)fy0;
            const float cw[4] = {a * (1.f - dx) * (1.f - dy), a * dx * (1.f - dy),
                                 a * (1.f - dx) * dy,         a * dx * dy};
            const int cx[4] = {x0, x0 + 1, x0, x0 + 1};
            const int cy[4] = {y0, y0, y0 + 1, y0 + 1};
            #pragma unroll
            for (int cn = 0; cn < 4; cn++) {
                const int xi = cx[cn], yi = cy[cn];
                const bool ok = (xi >= 0) & (xi < Wl) & (yi >= 0) & (yi < Hl);
                const float wgt = ok ? cw[cn] : 0.f;
                const int xc = min(max(xi, 0), Wl - 1);
                const int yc = min(max(yi, 0), Hl - 1);
                const uint4 v = *(const uint4*)(vb + (size_t)(st + yc * Wl + xc) * 32);
                const uint uu[4] = {v.x, v.y, v.z, v.w};
                #pragma unroll
                for (int i2 = 0; i2 < 4; i2++) {
                    acc[2 * i2]     += wgt * __uint_as_float(uu[i2] << 16);
                    acc[2 * i2 + 1] += wgt * __uint_as_float(uu[i2] & 0xffff0000u);
                }
            }
        }
    }

    uint4 o;
    o.x = (uint)f2bf(acc[0]) | ((uint)f2bf(acc[1]) << 16);
    o.y = (uint)f2bf(acc[2]) | ((uint)f2bf(acc[3]) << 16);
    o.z = (uint)f2bf(acc[4]) | ((uint)f2bf(acc[5]) << 16);
    o.w = (uint)f2bf(acc[6]) | ((uint)f2bf(acc[7]) << 16);
    *(uint4*)(samp + (size_t)q * 256 + h * 32 + cg * 8) = o;
}

// ---------------------------------------------------------------------------
// LayerNorm over D=256: v = (a32 ? a32 : bf(a16)) + bf(r16); out f32 or bf16.
// ---------------------------------------------------------------------------
__global__ __launch_bounds__(256) void ln_mix(
    const float* __restrict__ a32, const ushort* __restrict__ a16,
    const ushort* __restrict__ r16,
    const float* __restrict__ g, const float* __restrict__ be,
    float* __restrict__ o32, ushort* __restrict__ o16)
{
    const int row = blockIdx.x, t = threadIdx.x;
    const size_t base = (size_t)row * 256 + t;

    const float v = (a32 ? a32[base] : bf2f(a16[base])) + bf2f(r16[base]);

    __shared__ float red[4], red2[4];
    const int wid = t >> 6, lane = t & 63;

    float s = v;
    #pragma unroll
    for (int o = 32; o > 0; o >>= 1) s += __shfl_down(s, o);
    if (lane == 0) red[wid] = s;
    __syncthreads();
    const float mean = (red[0] + red[1] + red[2] + red[3]) * (1.f / 256.f);

    const float dv = v - mean;
    float s2 = dv * dv;
    #pragma unroll
    for (int o = 32; o > 0; o >>= 1) s2 += __shfl_down(s2, o);
    if (lane == 0) red2[wid] = s2;
    __syncthreads();
    const float var = (red2[0] + red2[1] + red2[2] + red2[3]) * (1.f / 256.f);

    const float res = dv * rsqrtf(var + EPS_) * g[t] + be[t];
    if (o32) o32[base] = res;
    else     o16[base] = f2bf(res);
}

// ---------------------------------------------------------------------------
extern "C" void kernel_launch(void* const* d_in, const int* in_sizes, int n_in,
                              void* d_out, int out_size, void* d_ws, size_t ws_size,
                              hipStream_t stream)
{
    const float* src    = (const float*)d_in[0];
    const float* pos    = (const float*)d_in[1];
    const float* refp   = (const float*)d_in[2];
    const float* W_off  = (const float*)d_in[5];
    const float* b_off  = (const float*)d_in[6];
    const float* W_attn = (const float*)d_in[7];
    const float* b_attn = (const float*)d_in[8];
    const float* W_val  = (const float*)d_in[9];
    const float* b_val  = (const float*)d_in[10];
    const float* W_out  = (const float*)d_in[11];
    const float* b_out  = (const float*)d_in[12];
    const float* g1     = (const float*)d_in[13];
    const float* be1    = (const float*)d_in[14];
    const float* W_ff1  = (const float*)d_in[15];
    const float* b_ff1  = (const float*)d_in[16];
    const float* W_ff2  = (const float*)d_in[17];
    const float* b_ff2  = (const float*)d_in[18];
    const float* g2     = (const float*)d_in[19];
    const float* be2    = (const float*)d_in[20];
    float* out = (float*)d_out;

    const size_t szMDh = (size_t)M_ * 256 * 2;      // 22,282,240 B
    const size_t szOAh = (size_t)M_ * 384 * 2;      // 33,423,360 B

    char* ws = (char*)d_ws;
    ushort* WT      = (ushort*)ws;                  // all weights, see wconv_all
    ushort* WT_val  = WT;
    ushort* WT_oa   = WT + 65536;
    ushort* WT_out  = WT + 163840;
    ushort* WT_ff1  = WT + 229376;
    ushort* WT_ff2  = WT + 491520;
    float*  bias_oa = (float*)(ws + 1507328);       // 384 floats

    const size_t o_src  = 2097152;                  // src_bf  -> samp, hbuf
    const size_t o_q    = o_src + szMDh;            // q_bf    -> attn_bf
    const size_t o_val  = o_q   + szMDh;            // value (head-major)
    const size_t o_oa   = o_val + szMDh;            // offaw [M][384]
    const size_t o_x    = o_oa  + szOAh;            // x_bf
    const size_t o_ffn  = o_x   + szMDh;            // ffn_bf
    // total = 2MB + 5*szMDh + szOAh = ~147 MB

    ushort* src_bf = (ushort*)(ws + o_src);
    ushort* q_bf   = (ushort*)(ws + o_q);
    ushort* val_hm = (ushort*)(ws + o_val);
    ushort* offaw  = (ushort*)(ws + o_oa);
    ushort* x_bf   = (ushort*)(ws + o_x);
    ushort* ffn_bf = (ushort*)(ws + o_ffn);
    ushort* samp_bf = src_bf;   // src_bf dead after value GEMM
    ushort* attn_bf = q_bf;     // q_bf dead after offattn GEMM
    ushort* hbuf    = src_bf;   // spans src+q+val+offaw = 4.5*szMDh >= M*1024*2

    // 0) all weight converts + bias concat (one dispatch)
    wconv_all<<<(753664 + 384 + 255) / 256, 256, 0, stream>>>(
        W_val, W_off, W_attn, W_out, W_ff1, W_ff2, b_off, b_attn, WT, bias_oa);
    // 1) activation converts
    cvt_pair<<<(M_ * 256 / 4 + 255) / 256, 256, 0, stream>>>(src, pos, src_bf, q_bf);
    // 2) value = src @ W_val + b_val  (head-major output)
    mgemm<<<dim3(2, M_ / 128), 256, 0, stream>>>(src_bf, WT_val, b_val, val_hm, M_, 256, 256, 0, 1);
    // 3) offaw = (src+pos) @ [W_off|W_attn] + [b_off|b_attn]
    mgemm<<<dim3(3, M_ / 128), 256, 0, stream>>>(q_bf, WT_oa, bias_oa, offaw, M_, 384, 256, 0, 0);
    // 4) sampling (softmax inline)
    sample3<<<M_ / 8, 256, 0, stream>>>(val_hm, offaw, refp, samp_bf);
    // 5) attn_out = samp @ W_out + b_out
    mgemm<<<dim3(2, M_ / 128), 256, 0, stream>>>(samp_bf, WT_out, b_out, attn_bf, M_, 256, 256, 0, 0);
    // 6) x = LN(src + attn)
    ln_mix<<<M_, 256, 0, stream>>>(src, nullptr, attn_bf, g1, be1, nullptr, x_bf);
    // 7) FFN1: h = relu(x @ W_ff1 + b_ff1)
    mgemm<<<dim3(8, M_ / 128), 256, 0, stream>>>(x_bf, WT_ff1, b_ff1, hbuf, M_, DFF_, 256, 1, 0);
    // 8) FFN2: ffn = h @ W_ff2 + b_ff2
    mgemm<<<dim3(2, M_ / 128), 256, 0, stream>>>(hbuf, WT_ff2, b_ff2, ffn_bf, M_, 256, DFF_, 0, 0);
    // 9) out = LN(x + ffn)
    ln_mix<<<M_, 256, 0, stream>>>(nullptr, x_bf, ffn_bf, g2, be2, out, nullptr);
}

// Round 4
// 362.827 us; speedup vs baseline: 1.0324x; 1.0324x over previous
//
#include <hip/hip_runtime.h>
#include <cstdint>
#include <cstddef>

#define B_   2
#define S_   21760
#define M_   (B_ * S_)     // 43520
#define D_   256
#define DFF_ 1024
#define EPS_ 1e-5f

typedef __attribute__((ext_vector_type(8))) short short8;
typedef __attribute__((ext_vector_type(4))) float f32x4;
typedef __attribute__((ext_vector_type(2))) float f32x2;

__device__ __forceinline__ ushort f2bf(float f) {
    uint x = __float_as_uint(f);
    return (ushort)((x + 0x7fffu + ((x >> 16) & 1u)) >> 16);
}
__device__ __forceinline__ float bf2f(ushort u) {
    return __uint_as_float(((uint)u) << 16);
}

// ---------------------------------------------------------------------------
// One-shot weight transpose+convert for ALL weights + off/attn bias concat.
// WT layout (ushort offsets): val@0, offattn@65536 (384 rows: 0-255=W_off,
// 256-383=W_attn), out@163840, ff1@229376, ff2@491520.
// ---------------------------------------------------------------------------
__global__ __launch_bounds__(256) void wconv_all(
    const float* __restrict__ Wval, const float* __restrict__ Woff,
    const float* __restrict__ Wattn, const float* __restrict__ Wout,
    const float* __restrict__ Wff1, const float* __restrict__ Wff2,
    const float* __restrict__ boff, const float* __restrict__ battn,
    ushort* __restrict__ WT, float* __restrict__ bias_oa)
{
    const int i = blockIdx.x * 256 + threadIdx.x;
    if (i < 65536) {
        const int n = i >> 8, k = i & 255;
        WT[i] = f2bf(Wval[(size_t)k * 256 + n]);
    } else if (i < 163840) {
        const int j = i - 65536;
        const int n = j >> 8, k = j & 255;
        WT[i] = (n < 256) ? f2bf(Woff[(size_t)k * 256 + n])
                          : f2bf(Wattn[(size_t)k * 128 + (n - 256)]);
    } else if (i < 229376) {
        const int j = i - 163840;
        const int n = j >> 8, k = j & 255;
        WT[i] = f2bf(Wout[(size_t)k * 256 + n]);
    } else if (i < 491520) {
        const int j = i - 229376;
        const int n = j >> 8, k = j & 255;
        WT[i] = f2bf(Wff1[(size_t)k * 1024 + n]);
    } else if (i < 753664) {
        const int j = i - 491520;
        const int n = j >> 10, k = j & 1023;
        WT[i] = f2bf(Wff2[(size_t)k * 256 + n]);
    } else if (i < 753664 + 384) {
        const int j = i - 753664;
        bias_oa[j] = (j < 256) ? boff[j] : battn[j - 256];
    }
}

// ---------------------------------------------------------------------------
// src_bf = bf16(src); q_bf = bf16(src + pos)
// ---------------------------------------------------------------------------
__global__ __launch_bounds__(256) void cvt_pair(
    const float* __restrict__ src, const float* __restrict__ pos,
    ushort* __restrict__ sb, ushort* __restrict__ qb)
{
    const size_t i = ((size_t)blockIdx.x * 256 + threadIdx.x) * 4;
    if (i >= (size_t)M_ * 256) return;
    const float4 s = *(const float4*)(src + i);
    const float4 p = *(const float4*)(pos + i);
    ushort4 so, qo;
    so.x = f2bf(s.x); so.y = f2bf(s.y); so.z = f2bf(s.z); so.w = f2bf(s.w);
    qo.x = f2bf(s.x + p.x); qo.y = f2bf(s.y + p.y);
    qo.z = f2bf(s.z + p.z); qo.w = f2bf(s.w + p.w);
    *(ushort4*)(sb + i) = so;
    *(ushort4*)(qb + i) = qo;
}

// ---------------------------------------------------------------------------
// bf16 MFMA GEMM: 128x128 tile, BK=32, 4 waves, 4x4 16x16x32 fragments.
// mode 0: C row-major [M][N] bf16.
// mode 2: C = fp8 e4m3, head-major value layout [b][h][loc][32].
// ---------------------------------------------------------------------------
__global__ __launch_bounds__(256) void mgemm(
    const ushort* __restrict__ A, const ushort* __restrict__ WT,
    const float* __restrict__ bias, ushort* __restrict__ C,
    int M, int N, int K, int relu, int mode)
{
    __shared__ __align__(16) ushort Als[128 * 32];
    __shared__ __align__(16) ushort Bls[128 * 32];

    const int tid = threadIdx.x;
    const int wv = tid >> 6, ln = tid & 63;
    const int m0 = blockIdx.y << 7, n0 = blockIdx.x << 7;
    const int wm = wv >> 1, wn = wv & 1;

    const int lrow = ln >> 2, lcol = (ln & 3) * 8;

    f32x4 acc[4][4];
    const f32x4 zz = {0.f, 0.f, 0.f, 0.f};
    #pragma unroll
    for (int i = 0; i < 4; i++)
        #pragma unroll
        for (int j = 0; j < 4; j++) acc[i][j] = zz;

    for (int k0 = 0; k0 < K; k0 += 32) {
        __syncthreads();
        #pragma unroll
        for (int r = 0; r < 2; ++r) {
            const int c = r * 4 + wv;
            const ushort* ga = A + (size_t)(m0 + c * 16 + lrow) * K + k0 + lcol;
            __builtin_amdgcn_global_load_lds(
                (const __attribute__((address_space(1))) uint*)ga,
                (__attribute__((address_space(3))) uint*)(Als + c * 512), 16, 0, 0);
            const ushort* gb = WT + (size_t)(n0 + c * 16 + lrow) * K + k0 + lcol;
            __builtin_amdgcn_global_load_lds(
                (const __attribute__((address_space(1))) uint*)gb,
                (__attribute__((address_space(3))) uint*)(Bls + c * 512), 16, 0, 0);
        }
        __syncthreads();

        const int fr = ln & 15, kb = (ln >> 4) * 8;
        short8 af[4], bfr[4];
        #pragma unroll
        for (int i = 0; i < 4; i++)
            af[i] = *(const short8*)&Als[(wm * 64 + i * 16 + fr) * 32 + kb];
        #pragma unroll
        for (int j = 0; j < 4; j++)
            bfr[j] = *(const short8*)&Bls[(wn * 64 + j * 16 + fr) * 32 + kb];
        #pragma unroll
        for (int i = 0; i < 4; i++)
            #pragma unroll
            for (int j = 0; j < 4; j++)
                acc[i][j] = __builtin_amdgcn_mfma_f32_16x16x32_bf16(
                    af[i], bfr[j], acc[i][j], 0, 0, 0);
    }

    uint8_t* C8 = (uint8_t*)C;
    const int fr = ln & 15, rq = (ln >> 4) * 4;
    #pragma unroll
    for (int j = 0; j < 4; j++) {
        const int col = n0 + wn * 64 + j * 16 + fr;
        const float bv = bias[col];
        #pragma unroll
        for (int i = 0; i < 4; i++) {
            #pragma unroll
            for (int r = 0; r < 4; r++) {
                const int row = m0 + wm * 64 + i * 16 + rq + r;
                float v = acc[i][j][r] + bv;
                if (relu) v = fmaxf(v, 0.f);
                if (mode == 0) {
                    C[(size_t)row * N + col] = f2bf(v);
                } else {
                    const int bb = (row >= S_) ? 1 : 0;
                    const int loc = row - bb * S_;
                    const int hh = col >> 5, ch = col & 31;
                    const int pk = __builtin_amdgcn_cvt_pk_fp8_f32(v, v, 0, false);
                    C8[((size_t)(bb * 8 + hh) * S_ + loc) * 32 + ch] = (uint8_t)(pk & 0xff);
                }
            }
        }
    }
}

// ---------------------------------------------------------------------------
// Deformable sampling, fp8 value, owner-lane math sharing.
// Block = 8 queries x 32 lanes; 4-lane group per (q,h); lane cg owns level cg.
// ---------------------------------------------------------------------------
__global__ __launch_bounds__(256) void sample4(
    const uint8_t* __restrict__ value, const ushort* __restrict__ offaw,
    const float* __restrict__ refp, ushort* __restrict__ samp)
{
    const int t = threadIdx.x;
    const int lane = t & 63;
    const int q = blockIdx.x * 8 + (t >> 5);
    const int w = t & 31;
    const int h = w >> 2, cg = w & 3;
    const int b = q / S_;

    // this lane owns level l = cg: samples s = 4*cg + j
    const int Wl = 128 >> cg;
    const float fW = (float)Wl;
    const int st = (cg == 0) ? 0 : (cg == 1) ? 16384 : (cg == 2) ? 20480 : 21504;

    // group softmax (each lane holds 4 logits)
    const ushort* awq = offaw + (size_t)q * 384 + 256 + h * 16 + cg * 4;
    const uint2 lg = *(const uint2*)awq;
    float l0 = bf2f((ushort)(lg.x & 0xffff)), l1 = bf2f((ushort)(lg.x >> 16));
    float l2 = bf2f((ushort)(lg.y & 0xffff)), l3 = bf2f((ushort)(lg.y >> 16));
    float mx = fmaxf(fmaxf(l0, l1), fmaxf(l2, l3));
    mx = fmaxf(mx, __shfl_xor(mx, 1));
    mx = fmaxf(mx, __shfl_xor(mx, 2));
    const float e0 = __expf(l0 - mx), e1 = __expf(l1 - mx);
    const float e2 = __expf(l2 - mx), e3 = __expf(l3 - mx);
    float sm = e0 + e1 + e2 + e3;
    sm += __shfl_xor(sm, 1);
    sm += __shfl_xor(sm, 2);
    const float inv = 1.f / sm;
    const float aj[4] = {e0 * inv, e1 * inv, e2 * inv, e3 * inv};

    // owner math: coords/weights/addresses for own 4 samples
    const ushort* ofq = offaw + (size_t)q * 384 + h * 32 + cg * 8;
    const uint4 of = *(const uint4*)ofq;
    const float rx = refp[(size_t)q * 8 + cg * 2];
    const float ry = refp[(size_t)q * 8 + cg * 2 + 1];
    const uint ou[4] = {of.x, of.y, of.z, of.w};

    float wt[4][4];
    int   ix[4][4];
    #pragma unroll
    for (int j = 0; j < 4; j++) {
        const float ox = bf2f((ushort)(ou[j] & 0xffff));
        const float oy = bf2f((ushort)(ou[j] >> 16));
        const float x = fmaf(rx, fW, ox) - 0.5f;
        const float y = fmaf(ry, fW, oy) - 0.5f;
        const float fx0 = floorf(x), fy0 = floorf(y);
        const float dx = x - fx0, dy = y - fy0;
        const int x0 = (int)fx0, y0 = (int)fy0;
        const float a = aj[j];
        const float cwv[4] = {a * (1.f - dx) * (1.f - dy), a * dx * (1.f - dy),
                              a * (1.f - dx) * dy,          a * dx * dy};
        const int cx[4] = {x0, x0 + 1, x0, x0 + 1};
        const int cy[4] = {y0, y0, y0 + 1, y0 + 1};
        #pragma unroll
        for (int c = 0; c < 4; c++) {
            const bool ok = (cx[c] >= 0) & (cx[c] < Wl) & (cy[c] >= 0) & (cy[c] < Wl);
            wt[j][c] = ok ? cwv[c] : 0.f;
            const int xc = min(max(cx[c], 0), Wl - 1);
            const int yc = min(max(cy[c], 0), Wl - 1);
            ix[j][c] = (st + yc * Wl + xc) * 32;
        }
    }

    // gather + accumulate (all 16 samples, weights/addresses via shuffle)
    const uint8_t* vb = value + ((size_t)(b * 8 + h) * S_) * 32 + cg * 8;
    f32x2 acc0 = {0.f, 0.f}, acc1 = {0.f, 0.f}, acc2 = {0.f, 0.f}, acc3 = {0.f, 0.f};
    const int gbase = lane & ~3;

    #pragma unroll
    for (int s = 0; s < 16; s++) {
        const int ol = s >> 2, j = s & 3;
        const int src = gbase + ol;
        #pragma unroll
        for (int c = 0; c < 4; c++) {
            const float wv = __shfl(wt[j][c], src, 64);
            const int   iv = __shfl(ix[j][c], src, 64);
            const uint2 u = *(const uint2*)(vb + iv);
            const f32x2 p0 = __builtin_amdgcn_cvt_pk_f32_fp8((int)u.x, false);
            const f32x2 p1 = __builtin_amdgcn_cvt_pk_f32_fp8((int)u.x, true);
            const f32x2 p2 = __builtin_amdgcn_cvt_pk_f32_fp8((int)u.y, false);
            const f32x2 p3 = __builtin_amdgcn_cvt_pk_f32_fp8((int)u.y, true);
            const f32x2 w2 = {wv, wv};
            acc0 += w2 * p0;
            acc1 += w2 * p1;
            acc2 += w2 * p2;
            acc3 += w2 * p3;
        }
    }

    uint4 o;
    o.x = (uint)f2bf(acc0.x) | ((uint)f2bf(acc0.y) << 16);
    o.y = (uint)f2bf(acc1.x) | ((uint)f2bf(acc1.y) << 16);
    o.z = (uint)f2bf(acc2.x) | ((uint)f2bf(acc2.y) << 16);
    o.w = (uint)f2bf(acc3.x) | ((uint)f2bf(acc3.y) << 16);
    *(uint4*)(samp + (size_t)q * 256 + h * 32 + cg * 8) = o;
}

// ---------------------------------------------------------------------------
// LayerNorm over D=256: v = (a32 ? a32 : bf(a16)) + bf(r16); out f32 or bf16.
// ---------------------------------------------------------------------------
__global__ __launch_bounds__(256) void ln_mix(
    const float* __restrict__ a32, const ushort* __restrict__ a16,
    const ushort* __restrict__ r16,
    const float* __restrict__ g, const float* __restrict__ be,
    float* __restrict__ o32, ushort* __restrict__ o16)
{
    const int row = blockIdx.x, t = threadIdx.x;
    const size_t base = (size_t)row * 256 + t;

    const float v = (a32 ? a32[base] : bf2f(a16[base])) + bf2f(r16[base]);

    __shared__ float red[4], red2[4];
    const int wid = t >> 6, lane = t & 63;

    float s = v;
    #pragma unroll
    for (int o = 32; o > 0; o >>= 1) s += __shfl_down(s, o);
    if (lane == 0) red[wid] = s;
    __syncthreads();
    const float mean = (red[0] + red[1] + red[2] + red[3]) * (1.f / 256.f);

    const float dv = v - mean;
    float s2 = dv * dv;
    #pragma unroll
    for (int o = 32; o > 0; o >>= 1) s2 += __shfl_down(s2, o);
    if (lane == 0) red2[wid] = s2;
    __syncthreads();
    const float var = (red2[0] + red2[1] + red2[2] + red2[3]) * (1.f / 256.f);

    const float res = dv * rsqrtf(var + EPS_) * g[t] + be[t];
    if (o32) o32[base] = res;
    else     o16[base] = f2bf(res);
}

// ---------------------------------------------------------------------------
extern "C" void kernel_launch(void* const* d_in, const int* in_sizes, int n_in,
                              void* d_out, int out_size, void* d_ws, size_t ws_size,
                              hipStream_t stream)
{
    const float* src    = (const float*)d_in[0];
    const float* pos    = (const float*)d_in[1];
    const float* refp   = (const float*)d_in[2];
    const float* W_off  = (const float*)d_in[5];
    const float* b_off  = (const float*)d_in[6];
    const float* W_attn = (const float*)d_in[7];
    const float* b_attn = (const float*)d_in[8];
    const float* W_val  = (const float*)d_in[9];
    const float* b_val  = (const float*)d_in[10];
    const float* W_out  = (const float*)d_in[11];
    const float* b_out  = (const float*)d_in[12];
    const float* g1     = (const float*)d_in[13];
    const float* be1    = (const float*)d_in[14];
    const float* W_ff1  = (const float*)d_in[15];
    const float* b_ff1  = (const float*)d_in[16];
    const float* W_ff2  = (const float*)d_in[17];
    const float* b_ff2  = (const float*)d_in[18];
    const float* g2     = (const float*)d_in[19];
    const float* be2    = (const float*)d_in[20];
    float* out = (float*)d_out;

    const size_t szMDh = (size_t)M_ * 256 * 2;      // 22,282,240 B
    const size_t szOAh = (size_t)M_ * 384 * 2;      // 33,423,360 B

    char* ws = (char*)d_ws;
    ushort* WT      = (ushort*)ws;
    ushort* WT_val  = WT;
    ushort* WT_oa   = WT + 65536;
    ushort* WT_out  = WT + 163840;
    ushort* WT_ff1  = WT + 229376;
    ushort* WT_ff2  = WT + 491520;
    float*  bias_oa = (float*)(ws + 1507328);

    const size_t o_src  = 2097152;                  // src_bf  -> samp, hbuf
    const size_t o_q    = o_src + szMDh;            // q_bf    -> attn_bf
    const size_t o_val  = o_q   + szMDh;            // value (fp8 head-major)
    const size_t o_oa   = o_val + szMDh;            // offaw [M][384]
    const size_t o_x    = o_oa  + szOAh;            // x_bf
    const size_t o_ffn  = o_x   + szMDh;            // ffn_bf

    ushort* src_bf = (ushort*)(ws + o_src);
    ushort* q_bf   = (ushort*)(ws + o_q);
    ushort* val_f8 = (ushort*)(ws + o_val);         // passed as C, used as fp8
    ushort* offaw  = (ushort*)(ws + o_oa);
    ushort* x_bf   = (ushort*)(ws + o_x);
    ushort* ffn_bf = (ushort*)(ws + o_ffn);
    ushort* samp_bf = src_bf;   // src_bf dead after value GEMM
    ushort* attn_bf = q_bf;     // q_bf dead after offattn GEMM
    ushort* hbuf    = src_bf;   // spans src+q+val+offaw >= M*1024*2

    // 0) all weight converts + bias concat
    wconv_all<<<(753664 + 384 + 255) / 256, 256, 0, stream>>>(
        W_val, W_off, W_attn, W_out, W_ff1, W_ff2, b_off, b_attn, WT, bias_oa);
    // 1) activation converts
    cvt_pair<<<(M_ * 256 / 4 + 255) / 256, 256, 0, stream>>>(src, pos, src_bf, q_bf);
    // 2) value = src @ W_val + b_val  (fp8 head-major output)
    mgemm<<<dim3(2, M_ / 128), 256, 0, stream>>>(src_bf, WT_val, b_val, val_f8, M_, 256, 256, 0, 2);
    // 3) offaw = (src+pos) @ [W_off|W_attn] + [b_off|b_attn]
    mgemm<<<dim3(3, M_ / 128), 256, 0, stream>>>(q_bf, WT_oa, bias_oa, offaw, M_, 384, 256, 0, 0);
    // 4) sampling (softmax inline, owner-lane shared math)
    sample4<<<M_ / 8, 256, 0, stream>>>((const uint8_t*)val_f8, offaw, refp, samp_bf);
    // 5) attn_out = samp @ W_out + b_out
    mgemm<<<dim3(2, M_ / 128), 256, 0, stream>>>(samp_bf, WT_out, b_out, attn_bf, M_, 256, 256, 0, 0);
    // 6) x = LN(src + attn)
    ln_mix<<<M_, 256, 0, stream>>>(src, nullptr, attn_bf, g1, be1, nullptr, x_bf);
    // 7) FFN1: h = relu(x @ W_ff1 + b_ff1)
    mgemm<<<dim3(8, M_ / 128), 256, 0, stream>>>(x_bf, WT_ff1, b_ff1, hbuf, M_, DFF_, 256, 1, 0);
    // 8) FFN2: ffn = h @ W_ff2 + b_ff2
    mgemm<<<dim3(2, M_ / 128), 256, 0, stream>>>(hbuf, WT_ff2, b_ff2, ffn_bf, M_, 256, DFF_, 0, 0);
    // 9) out = LN(x + ffn)
    ln_mix<<<M_, 256, 0, stream>>>(nullptr, x_bf, ffn_bf, g2, be2, out, nullptr);
}